// Round 2
// baseline (409.890 us; speedup 1.0000x reference)
//
#include <hip/hip_runtime.h>
#include <hip/hip_bf16.h>
#include <math.h>

#define BB 4
#define SEQ 2048
#define HEADS 16
#define DH 64
#define HID 1024
#define MM (BB*SEQ)
#define KK HID

typedef __attribute__((ext_vector_type(8))) short bf16x8;
typedef __attribute__((ext_vector_type(4))) float f32x4;
typedef unsigned short u16;
typedef unsigned int u32;

__device__ __forceinline__ u16 f2bf(float f){
  u32 u = __builtin_bit_cast(u32, f);
  u += 0x7fffu + ((u>>16)&1u);
  return (u16)(u>>16);
}

__device__ __forceinline__ uint4 pack8(const float4 a, const float4 b){
  uint4 r;
  r.x = (u32)f2bf(a.x) | ((u32)f2bf(a.y)<<16);
  r.y = (u32)f2bf(a.z) | ((u32)f2bf(a.w)<<16);
  r.z = (u32)f2bf(b.x) | ((u32)f2bf(b.y)<<16);
  r.w = (u32)f2bf(b.z) | ((u32)f2bf(b.w)<<16);
  return r;
}

#define MFMA(a,b,c) __builtin_amdgcn_mfma_f32_16x16x32_bf16(a,b,c,0,0,0)

// ---------------- RoPE cos/sin table: [pos][p] float2, p = 0..31 -------------
__global__ void rope_tab_kernel(float2* tab){
  int idx = blockIdx.x*256 + threadIdx.x;
  if (idx >= SEQ*32) return;
  int pos = idx >> 5, p = idx & 31;
  double inv = exp2(-(double)p * (13.287712379549449/32.0)); // 10000^(-p/32)
  double a = (double)pos * inv;
  tab[idx] = make_float2((float)cos(a), (float)sin(a));
}

// ---------------- padding-mask normalizer ------------------------------------
// The harness passes bool inputs as either int32 (documented int path) or raw
// uint8. Detect on-device: scan the first n/4 words (in-bounds under BOTH
// encodings); any word value >1 implies packed-uint8 (all-ones uint8 word =
// 0x01010101). Then write a canonical f32 bias array (0 / -1e30) to d_ws.
__global__ __launch_bounds__(1024)
void mask_bias_kernel(const int* pm, float* bias, int nelem){
  __shared__ int flag;
  if (threadIdx.x == 0) flag = 0;
  __syncthreads();
  int bad = 0;
  for (int i = threadIdx.x; i < nelem/4; i += 1024){
    u32 v = ((const u32*)pm)[i];
    if (v > 1u) bad = 1;
  }
  if (bad) atomicOr(&flag, 1);
  __syncthreads();
  const int u8mode = flag;
  for (int i = threadIdx.x; i < nelem; i += 1024){
    int v = u8mode ? (int)((const unsigned char*)pm)[i] : pm[i];
    bias[i] = v ? 0.f : -1e30f;
  }
}

// ---------------- GEMM: C = A @ W^T -----------------------------------------
// MODE 0: A f32, epilogue RoPE + *0.125, store bf16 scattered to (b,h,n,d)
// MODE 1: A f32, epilogue RoPE,          store bf16 scattered to (b,h,n,d)
// MODE 2: A f32, plain,                  store bf16 scattered to (b,h,n,d)
// MODE 3: A bf16, plain,                 store f32 row-major [m][c]
template<int MODE>
__global__ __launch_bounds__(256,2)
void gemm_k(const void* Ap, const float* W, void* outp, const float2* tab)
{
  constexpr int BK = 32;
  __shared__ u16 lA[128][40];   // 80B rows (16B-aligned) -> conflict-light b128
  __shared__ u16 lB[128][40];
  const int tid  = threadIdx.x;
  const int lane = tid & 63;
  const int wid  = tid >> 6;
  const int wr = wid >> 1, wc = wid & 1;
  const int bm = blockIdx.x, bn = blockIdx.y;
  const int arow0 = bm*128, brow0 = bn*128;

  f32x4 acc[4][4];
  #pragma unroll
  for (int i=0;i<4;i++)
    #pragma unroll
    for (int j=0;j<4;j++) acc[i][j] = (f32x4){0.f,0.f,0.f,0.f};

  const int sr = tid >> 2;   // 0..63
  const int sc = tid & 3;    // 0..3 (8 f32 each)

  const float* Af = (const float*)Ap;
  const u16*   Ab = (const u16*)Ap;

  float4 ra[2][2], rb[2][2];
  uint4  rab[2];

  auto loadA = [&](int k0){
    if constexpr (MODE==3){
      const u16* p = Ab + (size_t)(arow0 + (tid>>1))*KK + k0 + (tid&1)*16;
      rab[0] = *(const uint4*)(p);
      rab[1] = *(const uint4*)(p+8);
    } else {
      #pragma unroll
      for (int s=0;s<2;s++){
        const float* p = Af + (size_t)(arow0 + sr + s*64)*KK + k0 + sc*8;
        ra[s][0] = *(const float4*)p;
        ra[s][1] = *(const float4*)(p+4);
      }
    }
  };
  auto loadB = [&](int k0){
    #pragma unroll
    for (int s=0;s<2;s++){
      const float* p = W + (size_t)(brow0 + sr + s*64)*KK + k0 + sc*8;
      rb[s][0] = *(const float4*)p;
      rb[s][1] = *(const float4*)(p+4);
    }
  };

  loadA(0); loadB(0);

  for (int t=0; t<KK/BK; ++t){
    __syncthreads();
    if constexpr (MODE==3){
      *(uint4*)&lA[tid>>1][(tid&1)*16 + 0] = rab[0];
      *(uint4*)&lA[tid>>1][(tid&1)*16 + 8] = rab[1];
    } else {
      *(uint4*)&lA[sr   ][sc*8] = pack8(ra[0][0], ra[0][1]);
      *(uint4*)&lA[sr+64][sc*8] = pack8(ra[1][0], ra[1][1]);
    }
    *(uint4*)&lB[sr   ][sc*8] = pack8(rb[0][0], rb[0][1]);
    *(uint4*)&lB[sr+64][sc*8] = pack8(rb[1][0], rb[1][1]);
    __syncthreads();
    if (t+1 < KK/BK){ loadA((t+1)*BK); loadB((t+1)*BK); }

    bf16x8 af[4], bfr[4];
    const int g = lane >> 4, rr = lane & 15;
    #pragma unroll
    for (int i=0;i<4;i++) af[i]  = *(const bf16x8*)&lA[wr*64 + i*16 + rr][g*8];
    #pragma unroll
    for (int j=0;j<4;j++) bfr[j] = *(const bf16x8*)&lB[wc*64 + j*16 + rr][g*8];
    #pragma unroll
    for (int i=0;i<4;i++)
      #pragma unroll
      for (int j=0;j<4;j++)
        acc[i][j] = MFMA(af[i], bfr[j], acc[i][j]);
  }

  // epilogue
  #pragma unroll
  for (int i=0;i<4;i++){
    #pragma unroll
    for (int j=0;j<4;j++){
      #pragma unroll
      for (int r=0;r<4;r++){
        const int m = arow0 + wr*64 + i*16 + (lane>>4)*4 + r;
        const int c = brow0 + wc*64 + j*16 + (lane&15);
        float v = acc[i][j][r];
        if constexpr (MODE==3){
          ((float*)outp)[(size_t)m*HID + c] = v;
        } else {
          const int pos = m & (SEQ-1);
          const int bidx = m >> 11;
          const int h = c >> 6, dd = c & 63;
          float o;
          if constexpr (MODE<=1){
            float2 cs = tab[pos*32 + (dd>>1)];
            float vp = __shfl_xor(v, 1);
            o = ((dd&1)==0) ? (v*cs.x - vp*cs.y) : (v*cs.x + vp*cs.y);
            if constexpr (MODE==0) o *= 0.125f;   // fold 1/sqrt(64), exact
          } else {
            o = v;
          }
          ((u16*)outp)[(((size_t)(bidx*HEADS + h))*SEQ + pos)*DH + dd] = f2bf(o);
        }
      }
    }
  }
}

// ---------------- flash attention (causal/padded), bf16 in/out ---------------
__global__ __launch_bounds__(256,2)
void attn_k(const u16* q, const u16* kkp, const u16* vvp, u16* o,
            const float* bias_g, const int* pcaus, const int* psp)
{
  const int tid = threadIdx.x, lane = tid & 63, wid = tid >> 6;
  const int qt = blockIdx.x;          // 0..31
  const int bh = blockIdx.y;          // 0..63
  const int b  = bh >> 4;
  const int q0 = qt*64;
  const int causal = *pcaus;
  const int sp = *psp;

  __shared__ u16 lK[64*64];        // [row][64], 16B-granule XOR swizzle by row&7
  __shared__ u16 lV[64*64];        // V^T: [dd][kv], same swizzle
  __shared__ u16 lP[4][16*64];     // per-wave P scratch, same swizzle
  __shared__ float lbias[64];

  const size_t hbase = (size_t)bh * SEQ * DH;
  const int g = lane >> 4, rr = lane & 15;

  // Q fragments (rows fixed per wave), scale already folded at Q store
  bf16x8 qf[2];
  {
    const int qr = q0 + wid*16 + rr;
    const u16* p = q + hbase + (size_t)qr*DH + g*8;
    qf[0] = *(const bf16x8*)(p);
    qf[1] = *(const bf16x8*)(p+32);
  }

  f32x4 oacc[4];
  #pragma unroll
  for (int j=0;j<4;j++) oacc[j] = (f32x4){0.f,0.f,0.f,0.f};
  float mrun[4], lrun[4];
  #pragma unroll
  for (int r=0;r<4;r++){ mrun[r] = -1e30f; lrun[r] = 0.f; }

  int jmax = causal ? ((q0+63 > sp-1) ? q0+63 : sp-1) : (SEQ-1);
  if (jmax > SEQ-1) jmax = SEQ-1;
  const int ntile = (jmax + 64) >> 6;
  const int i0 = q0 + wid*16;

  for (int kt=0; kt<ntile; ++kt){
    const int j0 = kt*64;
    __syncthreads();
    // stage K tile (coalesced 32B/thread), swizzled b128 writes
    {
      const int gi = tid*2;
      const int row = gi>>3, gg = gi&7;
      const u16* ps = kkp + hbase + (size_t)(j0+row)*DH + gg*8;
      uint4 a  = *(const uint4*)ps;
      uint4 bq = *(const uint4*)(ps+8);
      *(uint4*)&lK[row*64 + ((gg   ^(row&7))*8)] = a;
      *(uint4*)&lK[row*64 + (((gg+1)^(row&7))*8)] = bq;
    }
    // stage V transposed: kv-major threads -> conflict-free b16 writes
    {
      const int kv = tid & 63;
      const int gd0 = (tid>>6)*2;
      #pragma unroll
      for (int s=0;s<2;s++){
        const int gd = gd0 + s;
        const u16* ps = vvp + hbase + (size_t)(j0+kv)*DH + gd*8;
        uint4 a = *(const uint4*)ps;
        u16 e[8]; *(uint4*)e = a;
        #pragma unroll
        for (int u=0;u<8;u++){
          const int dd = gd*8+u;
          lV[dd*64 + (((kv>>3)^(dd&7))*8) + (kv&7)] = e[u];
        }
      }
    }
    if (tid < 64){
      lbias[tid] = bias_g[b*SEQ + j0 + tid];
    }
    __syncthreads();

    // S = Q K^T  (both operands K-contiguous rows)
    f32x4 sf[4];
    #pragma unroll
    for (int nj=0;nj<4;nj++){
      const int krow = nj*16 + rr;
      const int sw = krow & 7;
      bf16x8 b0 = *(const bf16x8*)&lK[krow*64 + ((g    ^sw)*8)];
      bf16x8 b1 = *(const bf16x8*)&lK[krow*64 + (((g+4)^sw)*8)];
      f32x4 s = (f32x4){0.f,0.f,0.f,0.f};
      s = MFMA(qf[0], b0, s);
      s = MFMA(qf[1], b1, s);
      sf[nj] = s;
    }
    // bias + (diagonal-only) causal mask
    const bool needmask = causal && !((j0+63 < sp) || (i0 >= sp && j0+63 <= i0));
    #pragma unroll
    for (int nj=0;nj<4;nj++){
      const float bias = lbias[nj*16 + rr];
      #pragma unroll
      for (int r=0;r<4;r++){
        float s = sf[nj][r] + bias;
        if (needmask){
          const int ii = i0 + g*4 + r;
          const int jj = j0 + nj*16 + rr;
          const bool allow = (jj < sp) || (ii >= sp && ii >= jj);
          s = allow ? s : -1e30f;
        }
        sf[nj][r] = s;
      }
    }
    // online softmax (row reduce over 16 lanes within quarter)
    float fac[4];
    #pragma unroll
    for (int r=0;r<4;r++){
      float m = fmaxf(fmaxf(sf[0][r], sf[1][r]), fmaxf(sf[2][r], sf[3][r]));
      m = fmaxf(m, __shfl_xor(m,1));
      m = fmaxf(m, __shfl_xor(m,2));
      m = fmaxf(m, __shfl_xor(m,4));
      m = fmaxf(m, __shfl_xor(m,8));
      const float mn = fmaxf(mrun[r], m);
      fac[r] = __expf(mrun[r] - mn);
      mrun[r] = mn;
    }
    float rs[4] = {0.f,0.f,0.f,0.f};
    #pragma unroll
    for (int nj=0;nj<4;nj++)
      #pragma unroll
      for (int r=0;r<4;r++){
        const float p = __expf(sf[nj][r] - mrun[r]);
        sf[nj][r] = p;
        rs[r] += p;
      }
    #pragma unroll
    for (int r=0;r<4;r++){
      float s = rs[r];
      s += __shfl_xor(s,1); s += __shfl_xor(s,2);
      s += __shfl_xor(s,4); s += __shfl_xor(s,8);
      lrun[r] = lrun[r]*fac[r] + s;
    }
    #pragma unroll
    for (int j=0;j<4;j++)
      #pragma unroll
      for (int r=0;r<4;r++) oacc[j][r] *= fac[r];
    // P -> per-wave LDS scratch (A-frag layout after transpose)
    u16* myP = lP[wid];
    #pragma unroll
    for (int nj=0;nj<4;nj++)
      #pragma unroll
      for (int r=0;r<4;r++){
        const int prow = g*4 + r;
        const int pcol = nj*16 + rr;
        myP[prow*64 + (((pcol>>3)^(prow&7))*8) + (pcol&7)] = f2bf(sf[nj][r]);
      }
    __syncthreads();
    // O += P V
    #pragma unroll
    for (int f=0; f<2; f++){
      const int ga = g + 4*f;
      bf16x8 pa = *(const bf16x8*)&myP[rr*64 + ((ga^(rr&7))*8)];
      #pragma unroll
      for (int nd=0; nd<4; nd++){
        const int vrow = nd*16 + rr;
        bf16x8 vb = *(const bf16x8*)&lV[vrow*64 + ((ga^(vrow&7))*8)];
        oacc[nd] = MFMA(pa, vb, oacc[nd]);
      }
    }
  }

  // normalize + store to (b, n, h*d) bf16
  #pragma unroll
  for (int nd=0; nd<4; nd++)
    #pragma unroll
    for (int r=0;r<4;r++){
      const int ii = q0 + wid*16 + g*4 + r;
      const int dd = nd*16 + rr;
      const float val = oacc[nd][r] / lrun[r];
      o[(((size_t)b*SEQ) + ii)*HID + (size_t)(bh&15)*DH + dd] = f2bf(val);
    }
}

// -----------------------------------------------------------------------------
extern "C" void kernel_launch(void* const* d_in, const int* in_sizes, int n_in,
                              void* d_out, int out_size, void* d_ws, size_t ws_size,
                              hipStream_t stream)
{
  const float* x_q = (const float*)d_in[0];
  const float* x_k = (const float*)d_in[1];
  const float* x_v = (const float*)d_in[2];
  const float* W_q = (const float*)d_in[3];
  const float* W_k = (const float*)d_in[4];
  const float* W_v = (const float*)d_in[5];
  const float* W_o = (const float*)d_in[6];
  const int*   pm  = (const int*)d_in[7];
  const int* caus = (const int*)d_in[8];
  const int* sp   = (const int*)d_in[9];

  char* ws = (char*)d_ws;
  float2* tab  = (float2*)ws;                      // 512 KiB
  u16*  v_ws   = (u16*)(ws + (1u<<20));            // 16 MiB
  u16*  o_ws   = (u16*)(ws + (17u<<20));           // 16 MiB
  float* bias  = (float*)(ws + (33u<<20));         // 32 KiB
  // q,k scratch live inside d_out (32 MiB); stream order makes this race-free:
  // attn finishes before gemm<3> overwrites d_out with the final f32 result.
  u16* q_ws = (u16*)d_out;
  u16* k_ws = ((u16*)d_out) + (size_t)MM*HID;

  rope_tab_kernel<<<SEQ*32/256, 256, 0, stream>>>(tab);
  mask_bias_kernel<<<1, 1024, 0, stream>>>(pm, bias, BB*SEQ);

  dim3 gg(MM/128, HID/128);
  gemm_k<0><<<gg, 256, 0, stream>>>(x_q, W_q, q_ws, tab);
  gemm_k<1><<<gg, 256, 0, stream>>>(x_k, W_k, k_ws, tab);
  gemm_k<2><<<gg, 256, 0, stream>>>(x_v, W_v, v_ws, tab);

  dim3 ga(SEQ/64, BB*HEADS);
  attn_k<<<ga, 256, 0, stream>>>(q_ws, k_ws, v_ws, o_ws, bias, caus, sp);

  gemm_k<3><<<gg, 256, 0, stream>>>(o_ws, W_o, d_out, tab);
}

// Round 3
// 408.105 us; speedup vs baseline: 1.0044x; 1.0044x over previous
//
#include <hip/hip_runtime.h>
#include <hip/hip_bf16.h>
#include <math.h>

#define BB 4
#define SEQ 2048
#define HEADS 16
#define DH 64
#define HID 1024
#define MM (BB*SEQ)
#define KK HID

typedef __attribute__((ext_vector_type(8))) short bf16x8;
typedef __attribute__((ext_vector_type(4))) float f32x4;
typedef unsigned short u16;
typedef unsigned int u32;

__device__ __forceinline__ u16 f2bf(float f){
  u32 u = __builtin_bit_cast(u32, f);
  u += 0x7fffu + ((u>>16)&1u);
  return (u16)(u>>16);
}

__device__ __forceinline__ uint4 pack8(const float4 a, const float4 b){
  uint4 r;
  r.x = (u32)f2bf(a.x) | ((u32)f2bf(a.y)<<16);
  r.y = (u32)f2bf(a.z) | ((u32)f2bf(a.w)<<16);
  r.z = (u32)f2bf(b.x) | ((u32)f2bf(b.y)<<16);
  r.w = (u32)f2bf(b.z) | ((u32)f2bf(b.w)<<16);
  return r;
}

#define MFMA(a,b,c) __builtin_amdgcn_mfma_f32_16x16x32_bf16(a,b,c,0,0,0)

// ---------------- RoPE cos/sin table: [pos][p] float2, p = 0..31 -------------
__global__ void rope_tab_kernel(float2* tab){
  int idx = blockIdx.x*256 + threadIdx.x;
  if (idx >= SEQ*32) return;
  int pos = idx >> 5, p = idx & 31;
  double inv = exp2(-(double)p * (13.287712379549449/32.0)); // 10000^(-p/32)
  double a = (double)pos * inv;
  tab[idx] = make_float2((float)cos(a), (float)sin(a));
}

// ---------------- padding-mask normalizer (int32 or uint8 robust) ------------
__global__ __launch_bounds__(1024)
void mask_bias_kernel(const int* pm, float* bias, int nelem){
  __shared__ int flag;
  if (threadIdx.x == 0) flag = 0;
  __syncthreads();
  int bad = 0;
  for (int i = threadIdx.x; i < nelem/4; i += 1024){
    u32 v = ((const u32*)pm)[i];
    if (v > 1u) bad = 1;
  }
  if (bad) atomicOr(&flag, 1);
  __syncthreads();
  const int u8mode = flag;
  for (int i = threadIdx.x; i < nelem; i += 1024){
    int v = u8mode ? (int)((const unsigned char*)pm)[i] : pm[i];
    bias[i] = v ? 0.f : -1e30f;
  }
}

// ---------------- GEMM: C = A @ W^T -----------------------------------------
// MODE 0: A f32, epilogue RoPE + *0.125, store bf16 scattered to (b,h,n,d)
// MODE 1: A f32, epilogue RoPE,          store bf16 scattered to (b,h,n,d)
// MODE 2: A f32, plain,                  store bf16 TRANSPOSED to (b,h,d,n)
// MODE 3: A bf16, plain,                 store f32 row-major [m][c]
template<int MODE>
__global__ __launch_bounds__(256,2)
void gemm_k(const void* Ap, const float* W, void* outp, const float2* tab)
{
  constexpr int BK = 32;
  __shared__ u16 lA[128][40];
  __shared__ u16 lB[128][40];
  const int tid  = threadIdx.x;
  const int lane = tid & 63;
  const int wid  = tid >> 6;
  const int wr = wid >> 1, wc = wid & 1;
  const int bm = blockIdx.x, bn = blockIdx.y;
  const int arow0 = bm*128, brow0 = bn*128;

  f32x4 acc[4][4];
  #pragma unroll
  for (int i=0;i<4;i++)
    #pragma unroll
    for (int j=0;j<4;j++) acc[i][j] = (f32x4){0.f,0.f,0.f,0.f};

  const int sr = tid >> 2;
  const int sc = tid & 3;

  const float* Af = (const float*)Ap;
  const u16*   Ab = (const u16*)Ap;

  float4 ra[2][2], rb[2][2];
  uint4  rab[2];

  auto loadA = [&](int k0){
    if constexpr (MODE==3){
      const u16* p = Ab + (size_t)(arow0 + (tid>>1))*KK + k0 + (tid&1)*16;
      rab[0] = *(const uint4*)(p);
      rab[1] = *(const uint4*)(p+8);
    } else {
      #pragma unroll
      for (int s=0;s<2;s++){
        const float* p = Af + (size_t)(arow0 + sr + s*64)*KK + k0 + sc*8;
        ra[s][0] = *(const float4*)p;
        ra[s][1] = *(const float4*)(p+4);
      }
    }
  };
  auto loadB = [&](int k0){
    #pragma unroll
    for (int s=0;s<2;s++){
      const float* p = W + (size_t)(brow0 + sr + s*64)*KK + k0 + sc*8;
      rb[s][0] = *(const float4*)p;
      rb[s][1] = *(const float4*)(p+4);
    }
  };

  loadA(0); loadB(0);

  for (int t=0; t<KK/BK; ++t){
    __syncthreads();
    if constexpr (MODE==3){
      *(uint4*)&lA[tid>>1][(tid&1)*16 + 0] = rab[0];
      *(uint4*)&lA[tid>>1][(tid&1)*16 + 8] = rab[1];
    } else {
      *(uint4*)&lA[sr   ][sc*8] = pack8(ra[0][0], ra[0][1]);
      *(uint4*)&lA[sr+64][sc*8] = pack8(ra[1][0], ra[1][1]);
    }
    *(uint4*)&lB[sr   ][sc*8] = pack8(rb[0][0], rb[0][1]);
    *(uint4*)&lB[sr+64][sc*8] = pack8(rb[1][0], rb[1][1]);
    __syncthreads();
    if (t+1 < KK/BK){ loadA((t+1)*BK); loadB((t+1)*BK); }

    bf16x8 af[4], bfr[4];
    const int g = lane >> 4, rr = lane & 15;
    #pragma unroll
    for (int i=0;i<4;i++) af[i]  = *(const bf16x8*)&lA[wr*64 + i*16 + rr][g*8];
    #pragma unroll
    for (int j=0;j<4;j++) bfr[j] = *(const bf16x8*)&lB[wc*64 + j*16 + rr][g*8];
    #pragma unroll
    for (int i=0;i<4;i++)
      #pragma unroll
      for (int j=0;j<4;j++)
        acc[i][j] = MFMA(af[i], bfr[j], acc[i][j]);
  }

  // epilogue
  #pragma unroll
  for (int i=0;i<4;i++){
    #pragma unroll
    for (int j=0;j<4;j++){
      if constexpr (MODE==2){
        // transposed store: (b, h, d, n), 4 consecutive n per lane -> 8B store
        const int m0 = arow0 + wr*64 + i*16 + (lane>>4)*4;
        const int c  = brow0 + wc*64 + j*16 + (lane&15);
        const int pos = m0 & (SEQ-1);
        const int bidx = m0 >> 11;
        const int h = c >> 6, dd = c & 63;
        uint2 pk;
        pk.x = (u32)f2bf(acc[i][j][0]) | ((u32)f2bf(acc[i][j][1])<<16);
        pk.y = (u32)f2bf(acc[i][j][2]) | ((u32)f2bf(acc[i][j][3])<<16);
        *(uint2*)&((u16*)outp)[((size_t)(bidx*HEADS + h)*DH + dd)*SEQ + pos] = pk;
      } else {
        #pragma unroll
        for (int r=0;r<4;r++){
          const int m = arow0 + wr*64 + i*16 + (lane>>4)*4 + r;
          const int c = brow0 + wc*64 + j*16 + (lane&15);
          float v = acc[i][j][r];
          if constexpr (MODE==3){
            ((float*)outp)[(size_t)m*HID + c] = v;
          } else {
            const int pos = m & (SEQ-1);
            const int bidx = m >> 11;
            const int h = c >> 6, dd = c & 63;
            float2 cs = tab[pos*32 + (dd>>1)];
            float vp = __shfl_xor(v, 1);
            float o = ((dd&1)==0) ? (v*cs.x - vp*cs.y) : (v*cs.x + vp*cs.y);
            if constexpr (MODE==0) o *= 0.125f;   // fold 1/sqrt(64), exact
            ((u16*)outp)[(((size_t)(bidx*HEADS + h))*SEQ + pos)*DH + dd] = f2bf(o);
          }
        }
      }
    }
  }
}

// ---------------- flash attention: 128 q-rows/block, prefetch, V^T input -----
__global__ __launch_bounds__(256,2)
void attn_k(const u16* q, const u16* kkp, const u16* vtp, u16* o,
            const float* bias_g, const int* pcaus, const int* psp)
{
  const int tid = threadIdx.x, lane = tid & 63, wid = tid >> 6;
  const int q0 = blockIdx.x*128;
  const int bh = blockIdx.y;
  const int b  = bh >> 4;
  const int causal = *pcaus;
  const int sp = *psp;

  __shared__ u16 lK[64*64];        // K [kv][dh], XOR-swizzled 16B granules
  __shared__ u16 lV[64*64];        // V^T [dd][kv], same swizzle
  __shared__ u16 lP[4][16*64];     // per-wave P scratch (reused per rowgroup)
  __shared__ float lbias[64];

  const size_t hbase = (size_t)bh * SEQ * DH;
  const int g = lane >> 4, rr = lane & 15;

  // Q fragments: 2 rowgroups of 16 rows per wave (scale folded at Q store)
  bf16x8 qf[2][2];
  #pragma unroll
  for (int rg=0; rg<2; ++rg){
    const int qr = q0 + wid*32 + rg*16 + rr;
    const u16* p = q + hbase + (size_t)qr*DH + g*8;
    qf[rg][0] = *(const bf16x8*)(p);
    qf[rg][1] = *(const bf16x8*)(p+32);
  }

  f32x4 oacc[2][4];
  float mrun[2][4], lrun[2][4];
  #pragma unroll
  for (int rg=0; rg<2; ++rg){
    #pragma unroll
    for (int j=0;j<4;j++) oacc[rg][j] = (f32x4){0.f,0.f,0.f,0.f};
    #pragma unroll
    for (int r=0;r<4;r++){ mrun[rg][r] = -1e30f; lrun[rg][r] = 0.f; }
  }

  int jmax = causal ? ((q0+127 > sp-1) ? q0+127 : sp-1) : (SEQ-1);
  if (jmax > SEQ-1) jmax = SEQ-1;
  const int ntile = (jmax + 64) >> 6;

  // prefetch registers (T14 async-STAGE split)
  uint4 kreg0, kreg1, vreg0, vreg1; float breg = 0.f;
  const int srow = tid >> 2;        // 0..63 (kv row for K, dd row for V^T)
  const int sg   = (tid & 3)*2;     // 16B group 0,2,4,6
  auto issue = [&](int kt){
    const int j0 = kt*64;
    const u16* pk = kkp + hbase + (size_t)(j0+srow)*DH + sg*8;
    kreg0 = *(const uint4*)pk;  kreg1 = *(const uint4*)(pk+8);
    const u16* pv = vtp + hbase + (size_t)srow*SEQ + j0 + sg*8;
    vreg0 = *(const uint4*)pv;  vreg1 = *(const uint4*)(pv+8);
    if (tid < 64) breg = bias_g[b*SEQ + j0 + tid];
  };
  issue(0);

  for (int kt=0; kt<ntile; ++kt){
    const int j0 = kt*64;
    __syncthreads();   // prev tile's LDS reads complete
    {
      const int sw = srow & 7;
      *(uint4*)&lK[srow*64 + ((sg    ^sw)*8)] = kreg0;
      *(uint4*)&lK[srow*64 + (((sg+1)^sw)*8)] = kreg1;
      *(uint4*)&lV[srow*64 + ((sg    ^sw)*8)] = vreg0;
      *(uint4*)&lV[srow*64 + (((sg+1)^sw)*8)] = vreg1;
      if (tid < 64) lbias[tid] = breg;
    }
    __syncthreads();
    if (kt+1 < ntile) issue(kt+1);   // loads fly under this tile's compute

    u16* myP = lP[wid];
    #pragma unroll
    for (int rg=0; rg<2; ++rg){
      const int i0 = q0 + wid*32 + rg*16;
      if (causal && j0 >= sp && j0 > i0+15) continue;  // tile fully masked for rg

      // S = Q K^T
      f32x4 sf[4];
      __builtin_amdgcn_s_setprio(1);
      #pragma unroll
      for (int nj=0;nj<4;nj++){
        const int krow = nj*16 + rr;
        const int sw = krow & 7;
        bf16x8 b0 = *(const bf16x8*)&lK[krow*64 + ((g    ^sw)*8)];
        bf16x8 b1 = *(const bf16x8*)&lK[krow*64 + (((g+4)^sw)*8)];
        f32x4 s = (f32x4){0.f,0.f,0.f,0.f};
        s = MFMA(qf[rg][0], b0, s);
        s = MFMA(qf[rg][1], b1, s);
        sf[nj] = s;
      }
      __builtin_amdgcn_s_setprio(0);

      const bool needmask = causal && !((j0+63 < sp) || (i0 >= sp && j0+63 <= i0));
      #pragma unroll
      for (int nj=0;nj<4;nj++){
        const float bias = lbias[nj*16 + rr];
        #pragma unroll
        for (int r=0;r<4;r++){
          float s = sf[nj][r] + bias;
          if (needmask){
            const int ii = i0 + g*4 + r;
            const int jj = j0 + nj*16 + rr;
            const bool allow = (jj < sp) || (ii >= sp && ii >= jj);
            s = allow ? s : -1e30f;
          }
          sf[nj][r] = s;
        }
      }
      // online softmax over 16 lanes
      float fac[4];
      #pragma unroll
      for (int r=0;r<4;r++){
        float m = fmaxf(fmaxf(sf[0][r], sf[1][r]), fmaxf(sf[2][r], sf[3][r]));
        m = fmaxf(m, __shfl_xor(m,1));
        m = fmaxf(m, __shfl_xor(m,2));
        m = fmaxf(m, __shfl_xor(m,4));
        m = fmaxf(m, __shfl_xor(m,8));
        const float mn = fmaxf(mrun[rg][r], m);
        fac[r] = __expf(mrun[rg][r] - mn);
        mrun[rg][r] = mn;
      }
      float rs[4] = {0.f,0.f,0.f,0.f};
      #pragma unroll
      for (int nj=0;nj<4;nj++)
        #pragma unroll
        for (int r=0;r<4;r++){
          const float p = __expf(sf[nj][r] - mrun[rg][r]);
          sf[nj][r] = p;
          rs[r] += p;
        }
      #pragma unroll
      for (int r=0;r<4;r++){
        float s = rs[r];
        s += __shfl_xor(s,1); s += __shfl_xor(s,2);
        s += __shfl_xor(s,4); s += __shfl_xor(s,8);
        lrun[rg][r] = lrun[rg][r]*fac[r] + s;
      }
      #pragma unroll
      for (int j=0;j<4;j++)
        #pragma unroll
        for (int r=0;r<4;r++) oacc[rg][j][r] *= fac[r];
      // P -> per-wave LDS scratch (A-frag layout)
      #pragma unroll
      for (int nj=0;nj<4;nj++)
        #pragma unroll
        for (int r=0;r<4;r++){
          const int prow = g*4 + r;
          const int pcol = nj*16 + rr;
          myP[prow*64 + (((pcol>>3)^(prow&7))*8) + (pcol&7)] = f2bf(sf[nj][r]);
        }
      // O += P V
      __builtin_amdgcn_s_setprio(1);
      #pragma unroll
      for (int f=0; f<2; f++){
        const int ga = g + 4*f;
        bf16x8 pa = *(const bf16x8*)&myP[rr*64 + ((ga^(rr&7))*8)];
        #pragma unroll
        for (int nd=0; nd<4; nd++){
          const int vrow = nd*16 + rr;
          bf16x8 vb = *(const bf16x8*)&lV[vrow*64 + ((ga^(vrow&7))*8)];
          oacc[rg][nd] = MFMA(pa, vb, oacc[rg][nd]);
        }
      }
      __builtin_amdgcn_s_setprio(0);
    }
  }

  // normalize + store to (b, n, h*d) bf16
  #pragma unroll
  for (int rg=0; rg<2; ++rg)
    #pragma unroll
    for (int nd=0; nd<4; nd++)
      #pragma unroll
      for (int r=0;r<4;r++){
        const int ii = q0 + wid*32 + rg*16 + g*4 + r;
        const int dd = nd*16 + rr;
        const float val = oacc[rg][nd][r] / lrun[rg][r];
        o[(((size_t)b*SEQ) + ii)*HID + (size_t)(bh&15)*DH + dd] = f2bf(val);
      }
}

// -----------------------------------------------------------------------------
extern "C" void kernel_launch(void* const* d_in, const int* in_sizes, int n_in,
                              void* d_out, int out_size, void* d_ws, size_t ws_size,
                              hipStream_t stream)
{
  const float* x_q = (const float*)d_in[0];
  const float* x_k = (const float*)d_in[1];
  const float* x_v = (const float*)d_in[2];
  const float* W_q = (const float*)d_in[3];
  const float* W_k = (const float*)d_in[4];
  const float* W_v = (const float*)d_in[5];
  const float* W_o = (const float*)d_in[6];
  const int*   pm  = (const int*)d_in[7];
  const int* caus = (const int*)d_in[8];
  const int* sp   = (const int*)d_in[9];

  char* ws = (char*)d_ws;
  float2* tab  = (float2*)ws;                      // 512 KiB
  u16*  v_ws   = (u16*)(ws + (1u<<20));            // 16 MiB (V^T: b,h,d,n)
  u16*  o_ws   = (u16*)(ws + (17u<<20));           // 16 MiB
  float* bias  = (float*)(ws + (33u<<20));         // 32 KiB
  // q,k scratch live inside d_out (32 MiB); stream order makes this race-free.
  u16* q_ws = (u16*)d_out;
  u16* k_ws = ((u16*)d_out) + (size_t)MM*HID;

  rope_tab_kernel<<<SEQ*32/256, 256, 0, stream>>>(tab);
  mask_bias_kernel<<<1, 1024, 0, stream>>>(pm, bias, BB*SEQ);

  dim3 gg(MM/128, HID/128);
  gemm_k<0><<<gg, 256, 0, stream>>>(x_q, W_q, q_ws, tab);
  gemm_k<1><<<gg, 256, 0, stream>>>(x_k, W_k, k_ws, tab);
  gemm_k<2><<<gg, 256, 0, stream>>>(x_v, W_v, v_ws, tab);

  dim3 ga(SEQ/128, BB*HEADS);
  attn_k<<<ga, 256, 0, stream>>>(q_ws, k_ws, v_ws, o_ws, bias, caus, sp);

  gemm_k<3><<<gg, 256, 0, stream>>>(o_ws, W_o, d_out, tab);
}

// Round 4
// 382.619 us; speedup vs baseline: 1.0713x; 1.0666x over previous
//
#include <hip/hip_runtime.h>
#include <hip/hip_bf16.h>
#include <math.h>

#define BB 4
#define SEQ 2048
#define HEADS 16
#define DH 64
#define HID 1024
#define MM (BB*SEQ)
#define KK HID

typedef __attribute__((ext_vector_type(8))) short bf16x8;
typedef __attribute__((ext_vector_type(4))) float f32x4;
typedef unsigned short u16;
typedef unsigned int u32;

__device__ __forceinline__ u16 f2bf(float f){
  u32 u = __builtin_bit_cast(u32, f);
  u += 0x7fffu + ((u>>16)&1u);
  return (u16)(u>>16);
}

__device__ __forceinline__ uint4 pack8(const float4 a, const float4 b){
  uint4 r;
  r.x = (u32)f2bf(a.x) | ((u32)f2bf(a.y)<<16);
  r.y = (u32)f2bf(a.z) | ((u32)f2bf(a.w)<<16);
  r.z = (u32)f2bf(b.x) | ((u32)f2bf(b.y)<<16);
  r.w = (u32)f2bf(b.z) | ((u32)f2bf(b.w)<<16);
  return r;
}

#define MFMA(a,b,c) __builtin_amdgcn_mfma_f32_16x16x32_bf16(a,b,c,0,0,0)

// ---------------- RoPE cos/sin table: [pos][p] float2, p = 0..31 -------------
__global__ void rope_tab_kernel(float2* tab){
  int idx = blockIdx.x*256 + threadIdx.x;
  if (idx >= SEQ*32) return;
  int pos = idx >> 5, p = idx & 31;
  double inv = exp2(-(double)p * (13.287712379549449/32.0)); // 10000^(-p/32)
  double a = (double)pos * inv;
  tab[idx] = make_float2((float)cos(a), (float)sin(a));
}

// ---------------- padding-mask normalizer (int32 or uint8 robust) ------------
__global__ __launch_bounds__(1024)
void mask_bias_kernel(const int* pm, float* bias, int nelem){
  __shared__ int flag;
  if (threadIdx.x == 0) flag = 0;
  __syncthreads();
  int bad = 0;
  for (int i = threadIdx.x; i < nelem/4; i += 1024){
    u32 v = ((const u32*)pm)[i];
    if (v > 1u) bad = 1;
  }
  if (bad) atomicOr(&flag, 1);
  __syncthreads();
  const int u8mode = flag;
  for (int i = threadIdx.x; i < nelem; i += 1024){
    int v = u8mode ? (int)((const unsigned char*)pm)[i] : pm[i];
    bias[i] = v ? 0.f : -1e30f;
  }
}

// ---------------- GEMM: C = A @ W^T -----------------------------------------
// MODE 0: A f32, epilogue RoPE + *0.125, store bf16 scattered to (b,h,n,d)
// MODE 1: A f32, epilogue RoPE,          store bf16 scattered to (b,h,n,d)
// MODE 2: A f32, plain,                  store bf16 TRANSPOSED to (b,h,d,n)
// MODE 3: A bf16, plain,                 store f32 row-major [m][c]
template<int MODE>
__global__ __launch_bounds__(256,2)
void gemm_k(const void* Ap, const float* W, void* outp, const float2* tab)
{
  constexpr int BK = 32;
  __shared__ u16 lA[128][40];
  __shared__ u16 lB[128][40];
  const int tid  = threadIdx.x;
  const int lane = tid & 63;
  const int wid  = tid >> 6;
  const int wr = wid >> 1, wc = wid & 1;
  const int bm = blockIdx.x, bn = blockIdx.y;
  const int arow0 = bm*128, brow0 = bn*128;

  f32x4 acc[4][4];
  #pragma unroll
  for (int i=0;i<4;i++)
    #pragma unroll
    for (int j=0;j<4;j++) acc[i][j] = (f32x4){0.f,0.f,0.f,0.f};

  const int sr = tid >> 2;
  const int sc = tid & 3;

  const float* Af = (const float*)Ap;
  const u16*   Ab = (const u16*)Ap;

  float4 ra[2][2], rb[2][2];
  uint4  rab[2];

  auto loadA = [&](int k0){
    if constexpr (MODE==3){
      const u16* p = Ab + (size_t)(arow0 + (tid>>1))*KK + k0 + (tid&1)*16;
      rab[0] = *(const uint4*)(p);
      rab[1] = *(const uint4*)(p+8);
    } else {
      #pragma unroll
      for (int s=0;s<2;s++){
        const float* p = Af + (size_t)(arow0 + sr + s*64)*KK + k0 + sc*8;
        ra[s][0] = *(const float4*)p;
        ra[s][1] = *(const float4*)(p+4);
      }
    }
  };
  auto loadB = [&](int k0){
    #pragma unroll
    for (int s=0;s<2;s++){
      const float* p = W + (size_t)(brow0 + sr + s*64)*KK + k0 + sc*8;
      rb[s][0] = *(const float4*)p;
      rb[s][1] = *(const float4*)(p+4);
    }
  };

  loadA(0); loadB(0);

  for (int t=0; t<KK/BK; ++t){
    __syncthreads();
    if constexpr (MODE==3){
      *(uint4*)&lA[tid>>1][(tid&1)*16 + 0] = rab[0];
      *(uint4*)&lA[tid>>1][(tid&1)*16 + 8] = rab[1];
    } else {
      *(uint4*)&lA[sr   ][sc*8] = pack8(ra[0][0], ra[0][1]);
      *(uint4*)&lA[sr+64][sc*8] = pack8(ra[1][0], ra[1][1]);
    }
    *(uint4*)&lB[sr   ][sc*8] = pack8(rb[0][0], rb[0][1]);
    *(uint4*)&lB[sr+64][sc*8] = pack8(rb[1][0], rb[1][1]);
    __syncthreads();
    if (t+1 < KK/BK){ loadA((t+1)*BK); loadB((t+1)*BK); }

    bf16x8 af[4], bfr[4];
    const int g = lane >> 4, rr = lane & 15;
    #pragma unroll
    for (int i=0;i<4;i++) af[i]  = *(const bf16x8*)&lA[wr*64 + i*16 + rr][g*8];
    #pragma unroll
    for (int j=0;j<4;j++) bfr[j] = *(const bf16x8*)&lB[wc*64 + j*16 + rr][g*8];
    #pragma unroll
    for (int i=0;i<4;i++)
      #pragma unroll
      for (int j=0;j<4;j++)
        acc[i][j] = MFMA(af[i], bfr[j], acc[i][j]);
  }

  // epilogue
  #pragma unroll
  for (int i=0;i<4;i++){
    #pragma unroll
    for (int j=0;j<4;j++){
      if constexpr (MODE==2){
        // transposed store: (b, h, d, n), 4 consecutive n per lane -> 8B store
        const int m0 = arow0 + wr*64 + i*16 + (lane>>4)*4;
        const int c  = brow0 + wc*64 + j*16 + (lane&15);
        const int pos = m0 & (SEQ-1);
        const int bidx = m0 >> 11;
        const int h = c >> 6, dd = c & 63;
        uint2 pk;
        pk.x = (u32)f2bf(acc[i][j][0]) | ((u32)f2bf(acc[i][j][1])<<16);
        pk.y = (u32)f2bf(acc[i][j][2]) | ((u32)f2bf(acc[i][j][3])<<16);
        *(uint2*)&((u16*)outp)[((size_t)(bidx*HEADS + h)*DH + dd)*SEQ + pos] = pk;
      } else {
        #pragma unroll
        for (int r=0;r<4;r++){
          const int m = arow0 + wr*64 + i*16 + (lane>>4)*4 + r;
          const int c = brow0 + wc*64 + j*16 + (lane&15);
          float v = acc[i][j][r];
          if constexpr (MODE==3){
            ((float*)outp)[(size_t)m*HID + c] = v;
          } else {
            const int pos = m & (SEQ-1);
            const int bidx = m >> 11;
            const int h = c >> 6, dd = c & 63;
            float2 cs = tab[pos*32 + (dd>>1)];
            float vp = __shfl_xor(v, 1);
            float o = ((dd&1)==0) ? (v*cs.x - vp*cs.y) : (v*cs.x + vp*cs.y);
            if constexpr (MODE==0) o *= 0.125f;   // fold 1/sqrt(64), exact
            ((u16*)outp)[(((size_t)(bidx*HEADS + h))*SEQ + pos)*DH + dd] = f2bf(o);
          }
        }
      }
    }
  }
}

// ---------------- flash attention: causal-balanced paired q-tiles ------------
// Block x of 16 handles q-tile x AND q-tile 31-x (64 rows each): causal work
// per block is ~constant (~33 K-tiles) -> no tail imbalance. 3 blocks/CU.
__global__ __launch_bounds__(256,3)
void attn_k(const u16* q, const u16* kkp, const u16* vtp, u16* o,
            const float* bias_g, const int* pcaus, const int* psp)
{
  const int tid = threadIdx.x, lane = tid & 63, wid = tid >> 6;
  const int NQT = SEQ/64;                    // 32 q-tiles
  const int q0lo = blockIdx.x*64;
  const int q0hi = (NQT-1-(int)blockIdx.x)*64;
  const int bh = blockIdx.y;
  const int b  = bh >> 4;
  const int causal = *pcaus;
  const int sp = *psp;

  __shared__ u16 lK[64*64];        // K [kv][dh], XOR-swizzled 16B granules
  __shared__ u16 lV[64*64];        // V^T [dd][kv], same swizzle
  __shared__ u16 lP[4][16*64];     // per-wave P scratch
  __shared__ float lbias[64];

  const size_t hbase = (size_t)bh * SEQ * DH;
  const int g = lane >> 4, rr = lane & 15;

  // Q fragments: rg0 = 16 rows of lo tile, rg1 = 16 rows of hi tile
  bf16x8 qf[2][2];
  const int i0a[2] = { q0lo + wid*16, q0hi + wid*16 };
  #pragma unroll
  for (int rg=0; rg<2; ++rg){
    const u16* p = q + hbase + (size_t)(i0a[rg] + rr)*DH + g*8;
    qf[rg][0] = *(const bf16x8*)(p);
    qf[rg][1] = *(const bf16x8*)(p+32);
  }

  f32x4 oacc[2][4];
  float mrun[2][4], lrun[2][4];
  #pragma unroll
  for (int rg=0; rg<2; ++rg){
    #pragma unroll
    for (int j=0;j<4;j++) oacc[rg][j] = (f32x4){0.f,0.f,0.f,0.f};
    #pragma unroll
    for (int r=0;r<4;r++){ mrun[rg][r] = -1e30f; lrun[rg][r] = 0.f; }
  }

  // loop bound from hi tile (q0hi >= q0lo)
  int jmax = causal ? ((q0hi+63 > sp-1) ? q0hi+63 : sp-1) : (SEQ-1);
  if (jmax > SEQ-1) jmax = SEQ-1;
  const int ntile = (jmax + 64) >> 6;

  // prefetch registers (async-STAGE split)
  uint4 kreg0, kreg1, vreg0, vreg1; float breg = 0.f;
  const int srow = tid >> 2;        // 0..63
  const int sg   = (tid & 3)*2;     // 16B group 0,2,4,6
  auto issue = [&](int kt){
    const int j0 = kt*64;
    const u16* pk = kkp + hbase + (size_t)(j0+srow)*DH + sg*8;
    kreg0 = *(const uint4*)pk;  kreg1 = *(const uint4*)(pk+8);
    const u16* pv = vtp + hbase + (size_t)srow*SEQ + j0 + sg*8;
    vreg0 = *(const uint4*)pv;  vreg1 = *(const uint4*)(pv+8);
    if (tid < 64) breg = bias_g[b*SEQ + j0 + tid];
  };
  issue(0);

  for (int kt=0; kt<ntile; ++kt){
    const int j0 = kt*64;
    __syncthreads();   // prev tile's LDS reads complete
    {
      const int sw = srow & 7;
      *(uint4*)&lK[srow*64 + ((sg    ^sw)*8)] = kreg0;
      *(uint4*)&lK[srow*64 + (((sg+1)^sw)*8)] = kreg1;
      *(uint4*)&lV[srow*64 + ((sg    ^sw)*8)] = vreg0;
      *(uint4*)&lV[srow*64 + (((sg+1)^sw)*8)] = vreg1;
      if (tid < 64) lbias[tid] = breg;
    }
    __syncthreads();
    if (kt+1 < ntile) issue(kt+1);   // loads fly under this tile's compute

    bool act[2];
    #pragma unroll
    for (int rg=0; rg<2; ++rg)
      act[rg] = !(causal && j0 >= sp && j0 > i0a[rg]+15);

    // ---- QK^T for both rowgroups first (rg1 MFMAs overlap rg0 softmax) ----
    f32x4 sf[2][4];
    __builtin_amdgcn_s_setprio(1);
    #pragma unroll
    for (int rg=0; rg<2; ++rg){
      if (!act[rg]) continue;
      #pragma unroll
      for (int nj=0;nj<4;nj++){
        const int krow = nj*16 + rr;
        const int sw = krow & 7;
        bf16x8 b0 = *(const bf16x8*)&lK[krow*64 + ((g    ^sw)*8)];
        bf16x8 b1 = *(const bf16x8*)&lK[krow*64 + (((g+4)^sw)*8)];
        f32x4 s = (f32x4){0.f,0.f,0.f,0.f};
        s = MFMA(qf[rg][0], b0, s);
        s = MFMA(qf[rg][1], b1, s);
        sf[rg][nj] = s;
      }
    }
    __builtin_amdgcn_s_setprio(0);

    u16* myP = lP[wid];
    #pragma unroll
    for (int rg=0; rg<2; ++rg){
      if (!act[rg]) continue;
      const int i0 = i0a[rg];

      const bool needmask = causal && !((j0+63 < sp) || (i0 >= sp && j0+63 <= i0));
      #pragma unroll
      for (int nj=0;nj<4;nj++){
        const float bias = lbias[nj*16 + rr];
        #pragma unroll
        for (int r=0;r<4;r++){
          float s = sf[rg][nj][r] + bias;
          if (needmask){
            const int ii = i0 + g*4 + r;
            const int jj = j0 + nj*16 + rr;
            const bool allow = (jj < sp) || (ii >= sp && ii >= jj);
            s = allow ? s : -1e30f;
          }
          sf[rg][nj][r] = s;
        }
      }
      // online softmax over 16 lanes
      float fac[4];
      #pragma unroll
      for (int r=0;r<4;r++){
        float m = fmaxf(fmaxf(sf[rg][0][r], sf[rg][1][r]),
                        fmaxf(sf[rg][2][r], sf[rg][3][r]));
        m = fmaxf(m, __shfl_xor(m,1));
        m = fmaxf(m, __shfl_xor(m,2));
        m = fmaxf(m, __shfl_xor(m,4));
        m = fmaxf(m, __shfl_xor(m,8));
        const float mn = fmaxf(mrun[rg][r], m);
        fac[r] = __expf(mrun[rg][r] - mn);
        mrun[rg][r] = mn;
      }
      float rs[4] = {0.f,0.f,0.f,0.f};
      #pragma unroll
      for (int nj=0;nj<4;nj++)
        #pragma unroll
        for (int r=0;r<4;r++){
          const float p = __expf(sf[rg][nj][r] - mrun[rg][r]);
          sf[rg][nj][r] = p;
          rs[r] += p;
        }
      #pragma unroll
      for (int r=0;r<4;r++){
        float s = rs[r];
        s += __shfl_xor(s,1); s += __shfl_xor(s,2);
        s += __shfl_xor(s,4); s += __shfl_xor(s,8);
        lrun[rg][r] = lrun[rg][r]*fac[r] + s;
      }
      #pragma unroll
      for (int j=0;j<4;j++)
        #pragma unroll
        for (int r=0;r<4;r++) oacc[rg][j][r] *= fac[r];
      // P -> per-wave LDS scratch (A-frag layout)
      #pragma unroll
      for (int nj=0;nj<4;nj++)
        #pragma unroll
        for (int r=0;r<4;r++){
          const int prow = g*4 + r;
          const int pcol = nj*16 + rr;
          myP[prow*64 + (((pcol>>3)^(prow&7))*8) + (pcol&7)] = f2bf(sf[rg][nj][r]);
        }
      // O += P V  (these MFMAs overlap the other rowgroup's softmax VALU)
      __builtin_amdgcn_s_setprio(1);
      #pragma unroll
      for (int f=0; f<2; f++){
        const int ga = g + 4*f;
        bf16x8 pa = *(const bf16x8*)&myP[rr*64 + ((ga^(rr&7))*8)];
        #pragma unroll
        for (int nd=0; nd<4; nd++){
          const int vrow = nd*16 + rr;
          bf16x8 vb = *(const bf16x8*)&lV[vrow*64 + ((ga^(vrow&7))*8)];
          oacc[rg][nd] = MFMA(pa, vb, oacc[rg][nd]);
        }
      }
      __builtin_amdgcn_s_setprio(0);
    }
  }

  // normalize + store to (b, n, h*d) bf16
  #pragma unroll
  for (int rg=0; rg<2; ++rg)
    #pragma unroll
    for (int nd=0; nd<4; nd++)
      #pragma unroll
      for (int r=0;r<4;r++){
        const int ii = i0a[rg] + g*4 + r;
        const int dd = nd*16 + rr;
        const float val = oacc[rg][nd][r] / lrun[rg][r];
        o[(((size_t)b*SEQ) + ii)*HID + (size_t)(bh&15)*DH + dd] = f2bf(val);
      }
}

// -----------------------------------------------------------------------------
extern "C" void kernel_launch(void* const* d_in, const int* in_sizes, int n_in,
                              void* d_out, int out_size, void* d_ws, size_t ws_size,
                              hipStream_t stream)
{
  const float* x_q = (const float*)d_in[0];
  const float* x_k = (const float*)d_in[1];
  const float* x_v = (const float*)d_in[2];
  const float* W_q = (const float*)d_in[3];
  const float* W_k = (const float*)d_in[4];
  const float* W_v = (const float*)d_in[5];
  const float* W_o = (const float*)d_in[6];
  const int*   pm  = (const int*)d_in[7];
  const int* caus = (const int*)d_in[8];
  const int* sp   = (const int*)d_in[9];

  char* ws = (char*)d_ws;
  float2* tab  = (float2*)ws;                      // 512 KiB
  u16*  v_ws   = (u16*)(ws + (1u<<20));            // 16 MiB (V^T: b,h,d,n)
  u16*  o_ws   = (u16*)(ws + (17u<<20));           // 16 MiB
  float* bias  = (float*)(ws + (33u<<20));         // 32 KiB
  // q,k scratch live inside d_out (32 MiB); stream order makes this race-free.
  u16* q_ws = (u16*)d_out;
  u16* k_ws = ((u16*)d_out) + (size_t)MM*HID;

  rope_tab_kernel<<<SEQ*32/256, 256, 0, stream>>>(tab);
  mask_bias_kernel<<<1, 1024, 0, stream>>>(pm, bias, BB*SEQ);

  dim3 gg(MM/128, HID/128);
  gemm_k<0><<<gg, 256, 0, stream>>>(x_q, W_q, q_ws, tab);
  gemm_k<1><<<gg, 256, 0, stream>>>(x_k, W_k, k_ws, tab);
  gemm_k<2><<<gg, 256, 0, stream>>>(x_v, W_v, v_ws, tab);

  dim3 ga(SEQ/128, BB*HEADS);   // 16 paired blocks x 64 bh
  attn_k<<<ga, 256, 0, stream>>>(q_ws, k_ws, v_ws, o_ws, bias, caus, sp);

  gemm_k<3><<<gg, 256, 0, stream>>>(o_ws, W_o, d_out, tab);
}

// Round 5
// 303.477 us; speedup vs baseline: 1.3506x; 1.2608x over previous
//
#include <hip/hip_runtime.h>
#include <hip/hip_bf16.h>
#include <math.h>

#define BB 4
#define SEQ 2048
#define HEADS 16
#define DH 64
#define HID 1024
#define MM (BB*SEQ)
#define KK HID

typedef __attribute__((ext_vector_type(8))) short bf16x8;
typedef __attribute__((ext_vector_type(4))) float f32x4;
typedef __attribute__((ext_vector_type(16))) float f32x16;
typedef unsigned short u16;
typedef unsigned int u32;

__device__ __forceinline__ u16 f2bf(float f){
  u32 u = __builtin_bit_cast(u32, f);
  u += 0x7fffu + ((u>>16)&1u);
  return (u16)(u>>16);
}

__device__ __forceinline__ uint4 pack8(const float4 a, const float4 b){
  uint4 r;
  r.x = (u32)f2bf(a.x) | ((u32)f2bf(a.y)<<16);
  r.y = (u32)f2bf(a.z) | ((u32)f2bf(a.w)<<16);
  r.z = (u32)f2bf(b.x) | ((u32)f2bf(b.y)<<16);
  r.w = (u32)f2bf(b.z) | ((u32)f2bf(b.w)<<16);
  return r;
}

#define MFMA(a,b,c)   __builtin_amdgcn_mfma_f32_16x16x32_bf16(a,b,c,0,0,0)
#define MFMA32(a,b,c) __builtin_amdgcn_mfma_f32_32x32x16_bf16(a,b,c,0,0,0)

__device__ __forceinline__ void gload16(const u16* g, u16* l){
  __builtin_amdgcn_global_load_lds(
    (const __attribute__((address_space(1))) unsigned int*)(const void*)g,
    (__attribute__((address_space(3))) unsigned int*)(void*)l, 16, 0, 0);
}

// ---------------- RoPE cos/sin table: [pos][p] float2, p = 0..31 -------------
__global__ void rope_tab_kernel(float2* tab){
  int idx = blockIdx.x*256 + threadIdx.x;
  if (idx >= SEQ*32) return;
  int pos = idx >> 5, p = idx & 31;
  double inv = exp2(-(double)p * (13.287712379549449/32.0)); // 10000^(-p/32)
  double a = (double)pos * inv;
  tab[idx] = make_float2((float)cos(a), (float)sin(a));
}

// ---------------- padding-mask normalizer (int32 or uint8 robust) ------------
__global__ __launch_bounds__(1024)
void mask_bias_kernel(const int* pm, float* bias, u32* flagbits, int nelem){
  __shared__ int flag;
  if (threadIdx.x == 0) flag = 0;
  if (threadIdx.x < BB) flagbits[threadIdx.x] = 0u;
  __syncthreads();
  int bad = 0;
  for (int i = threadIdx.x; i < nelem/4; i += 1024){
    u32 v = ((const u32*)pm)[i];
    if (v > 1u) bad = 1;
  }
  if (bad) atomicOr(&flag, 1);
  __syncthreads();
  const int u8mode = flag;
  for (int i = threadIdx.x; i < nelem; i += 1024){
    int v = u8mode ? (int)((const unsigned char*)pm)[i] : pm[i];
    bias[i] = v ? 0.f : -__builtin_inff();
    if (!v) atomicOr(&flagbits[i>>11], 1u << ((i & (SEQ-1)) >> 6));
  }
}

// ---------------- GEMM: C = A @ W^T -----------------------------------------
// MODE 0: A f32, RoPE + *(0.125*log2e), bf16 scatter to (b,h,n,d)   [Q]
// MODE 1: A f32, RoPE,                  bf16 scatter to (b,h,n,d)   [K]
// MODE 2: A f32, plain, bf16 TRANSPOSED store to (b,h,d,n)          [V^T]
// MODE 3: A bf16, plain, f32 row-major [m][c]                        [out]
template<int MODE>
__global__ __launch_bounds__(256,2)
void gemm_k(const void* Ap, const float* W, void* outp, const float2* tab)
{
  constexpr int BK = 32;
  __shared__ u16 lA[128][40];
  __shared__ u16 lB[128][40];
  const int tid  = threadIdx.x;
  const int lane = tid & 63;
  const int wid  = tid >> 6;
  const int wr = wid >> 1, wc = wid & 1;
  const int bm = blockIdx.x, bn = blockIdx.y;
  const int arow0 = bm*128, brow0 = bn*128;

  f32x4 acc[4][4];
  #pragma unroll
  for (int i=0;i<4;i++)
    #pragma unroll
    for (int j=0;j<4;j++) acc[i][j] = (f32x4){0.f,0.f,0.f,0.f};

  const int sr = tid >> 2;
  const int sc = tid & 3;

  const float* Af = (const float*)Ap;
  const u16*   Ab = (const u16*)Ap;

  float4 ra[2][2], rb[2][2];
  uint4  rab[2];

  auto loadA = [&](int k0){
    if constexpr (MODE==3){
      const u16* p = Ab + (size_t)(arow0 + (tid>>1))*KK + k0 + (tid&1)*16;
      rab[0] = *(const uint4*)(p);
      rab[1] = *(const uint4*)(p+8);
    } else {
      #pragma unroll
      for (int s=0;s<2;s++){
        const float* p = Af + (size_t)(arow0 + sr + s*64)*KK + k0 + sc*8;
        ra[s][0] = *(const float4*)p;
        ra[s][1] = *(const float4*)(p+4);
      }
    }
  };
  auto loadB = [&](int k0){
    #pragma unroll
    for (int s=0;s<2;s++){
      const float* p = W + (size_t)(brow0 + sr + s*64)*KK + k0 + sc*8;
      rb[s][0] = *(const float4*)p;
      rb[s][1] = *(const float4*)(p+4);
    }
  };

  loadA(0); loadB(0);

  for (int t=0; t<KK/BK; ++t){
    __syncthreads();
    if constexpr (MODE==3){
      *(uint4*)&lA[tid>>1][(tid&1)*16 + 0] = rab[0];
      *(uint4*)&lA[tid>>1][(tid&1)*16 + 8] = rab[1];
    } else {
      *(uint4*)&lA[sr   ][sc*8] = pack8(ra[0][0], ra[0][1]);
      *(uint4*)&lA[sr+64][sc*8] = pack8(ra[1][0], ra[1][1]);
    }
    *(uint4*)&lB[sr   ][sc*8] = pack8(rb[0][0], rb[0][1]);
    *(uint4*)&lB[sr+64][sc*8] = pack8(rb[1][0], rb[1][1]);
    __syncthreads();
    if (t+1 < KK/BK){ loadA((t+1)*BK); loadB((t+1)*BK); }

    bf16x8 af[4], bfr[4];
    const int g = lane >> 4, rr = lane & 15;
    #pragma unroll
    for (int i=0;i<4;i++) af[i]  = *(const bf16x8*)&lA[wr*64 + i*16 + rr][g*8];
    #pragma unroll
    for (int j=0;j<4;j++) bfr[j] = *(const bf16x8*)&lB[wc*64 + j*16 + rr][g*8];
    #pragma unroll
    for (int i=0;i<4;i++)
      #pragma unroll
      for (int j=0;j<4;j++)
        acc[i][j] = MFMA(af[i], bfr[j], acc[i][j]);
  }

  // epilogue
  #pragma unroll
  for (int i=0;i<4;i++){
    #pragma unroll
    for (int j=0;j<4;j++){
      if constexpr (MODE==2){
        const int m0 = arow0 + wr*64 + i*16 + (lane>>4)*4;
        const int c  = brow0 + wc*64 + j*16 + (lane&15);
        const int pos = m0 & (SEQ-1);
        const int bidx = m0 >> 11;
        const int h = c >> 6, dd = c & 63;
        uint2 pk;
        pk.x = (u32)f2bf(acc[i][j][0]) | ((u32)f2bf(acc[i][j][1])<<16);
        pk.y = (u32)f2bf(acc[i][j][2]) | ((u32)f2bf(acc[i][j][3])<<16);
        *(uint2*)&((u16*)outp)[((size_t)(bidx*HEADS + h)*DH + dd)*SEQ + pos] = pk;
      } else {
        #pragma unroll
        for (int r=0;r<4;r++){
          const int m = arow0 + wr*64 + i*16 + (lane>>4)*4 + r;
          const int c = brow0 + wc*64 + j*16 + (lane&15);
          float v = acc[i][j][r];
          if constexpr (MODE==3){
            ((float*)outp)[(size_t)m*HID + c] = v;
          } else {
            const int pos = m & (SEQ-1);
            const int bidx = m >> 11;
            const int h = c >> 6, dd = c & 63;
            float2 cs = tab[pos*32 + (dd>>1)];
            float vp = __shfl_xor(v, 1);
            float o = ((dd&1)==0) ? (v*cs.x - vp*cs.y) : (v*cs.x + vp*cs.y);
            if constexpr (MODE==0) o *= 0.18033688011112042f; // 0.125*log2(e)
            ((u16*)outp)[(((size_t)(bidx*HEADS + h))*SEQ + pos)*DH + dd] = f2bf(o);
          }
        }
      }
    }
  }
}

// ---------------- flash attention: swapped-operand 32x32, lane-local softmax -
// Per wave: 32 q rows. S^T = mfma32(K, Q) -> q = lane&31 lane-local.
// O^T = mfma32(V^T, P^T) -> same locality; m/l/rescale are per-lane scalars.
// LDS double-buffered via global_load_lds (pre-swizzled source, swizzled read).
__global__ __launch_bounds__(256,3)
void attn_k(const u16* q, const u16* kkp, const u16* vtp, u16* o,
            const float* bias_g, const u32* flagbits, const int* pcaus, const int* psp)
{
  const int tid = threadIdx.x, lane = tid & 63, wid = tid >> 6;
  const int NQT = SEQ/64;
  const int q0lo = blockIdx.x*64;
  const int q0hi = (NQT-1-(int)blockIdx.x)*64;
  const int bh = blockIdx.y, b = bh >> 4;
  const int causal = *pcaus, sp = *psp;

  __shared__ u16 lK[2][64*64];
  __shared__ u16 lV[2][64*64];

  const size_t hbase = (size_t)bh * SEQ * DH;
  const int h = lane >> 5, ln31 = lane & 31, ln7 = lane & 7;

  const int i0w = (wid < 2) ? (q0lo + wid*32) : (q0hi + (wid-2)*32);
  const int myq = i0w + ln31;
  const u32 fbits = flagbits[b];

  // Q B-fragments (q = lane&31, d = 16s + 8h + j), held all loop
  bf16x8 qf[4];
  {
    const u16* qr = q + hbase + (size_t)myq*DH;
    #pragma unroll
    for (int s=0;s<4;s++) qf[s] = *(const bf16x8*)(qr + 16*s + 8*h);
  }

  // loop-invariant swizzled granule offsets (u16 units)
  int swz[4];
  #pragma unroll
  for (int s=0;s<4;s++) swz[s] = ((2*s + h) ^ ln7) * 8;

  f32x16 oac[2];
  #pragma unroll
  for (int t=0;t<16;t++){ oac[0][t] = 0.f; oac[1][t] = 0.f; }
  float mrun = -__builtin_inff(), lrun = 0.f;

  int jmax = causal ? ((q0hi+63 > sp-1) ? q0hi+63 : sp-1) : (SEQ-1);
  if (jmax > SEQ-1) jmax = SEQ-1;
  const int ntile = (jmax >> 6) + 1;

  auto stage = [&](int buf, int kt){
    const int j0 = kt*64;
    #pragma unroll
    for (int c=0;c<2;c++){
      const int row = wid*16 + c*8 + (lane>>3);
      const int sl  = (ln7 ^ (lane>>3)) * 8;   // pre-swizzled source granule
      gload16(kkp + hbase + (size_t)(j0+row)*DH + sl, &lK[buf][(wid*16+c*8)*64]);
      gload16(vtp + hbase + (size_t)row*SEQ + j0 + sl, &lV[buf][(wid*16+c*8)*64]);
    }
  };

  stage(0, 0);
  __syncthreads();
  int cur = 0;

  for (int kt=0; kt<ntile; ++kt){
    const int j0 = kt*64;
    if (kt+1 < ntile) stage(cur^1, kt+1);   // async into other buffer

    const bool active = !(causal && j0 >= sp && j0 > i0w+31);
    if (active){
      const u16* Kb = lK[cur];
      const u16* Vb = lV[cur];

      // ---- S^T = K · Q^T (two kv-halves of 32) ----
      f32x16 sA, sB;
      #pragma unroll
      for (int t=0;t<16;t++){ sA[t] = 0.f; sB[t] = 0.f; }
      __builtin_amdgcn_s_setprio(1);
      #pragma unroll
      for (int s=0;s<4;s++){
        bf16x8 k0 = *(const bf16x8*)&Kb[ ln31    *64 + swz[s]];
        bf16x8 k1 = *(const bf16x8*)&Kb[(32+ln31)*64 + swz[s]];
        sA = MFMA32(k0, qf[s], sA);
        sB = MFMA32(k1, qf[s], sB);
      }
      __builtin_amdgcn_s_setprio(0);

      // gather into s[32]: s[t] -> kv j0 + 32*(t>>4) + r(t&15)
      float sv[32];
      #pragma unroll
      for (int t=0;t<16;t++){ sv[t] = sA[t]; sv[16+t] = sB[t]; }

      // padding bias (slow path; never taken when mask all-true)
      if ((fbits >> kt) & 1u){
        #pragma unroll
        for (int t=0;t<32;t++){
          const int rt = ((t&3) + 8*((t&15)>>2) + 4*h) + 32*(t>>4);
          sv[t] += bias_g[b*SEQ + j0 + rt];
        }
      }
      // causal mask (diagonal tiles only)
      const bool needmask = causal && !((j0+63 < sp) || (i0w >= sp && j0+63 <= i0w));
      if (needmask){
        #pragma unroll
        for (int t=0;t<32;t++){
          const int jj = j0 + ((t&3) + 8*((t&15)>>2) + 4*h) + 32*(t>>4);
          const bool allow = (jj < sp) || (myq >= sp && myq >= jj);
          sv[t] = allow ? sv[t] : -__builtin_inff();
        }
      }

      // ---- online softmax, per-lane scalars, log2 domain ----
      float m8[8];
      #pragma unroll
      for (int t=0;t<8;t++)
        m8[t] = fmaxf(fmaxf(sv[t], sv[t+8]), fmaxf(sv[t+16], sv[t+24]));
      float m4a = fmaxf(fmaxf(m8[0],m8[1]), fmaxf(m8[2],m8[3]));
      float m4b = fmaxf(fmaxf(m8[4],m8[5]), fmaxf(m8[6],m8[7]));
      float pmax = fmaxf(m4a, m4b);
      pmax = fmaxf(pmax, __shfl_xor(pmax, 32));
      const float mnew = fmaxf(mrun, pmax);
      if (!__all(pmax - mrun <= 8.f)){       // defer-max (T13)
        const float fac = exp2f(mrun - mnew);
        mrun = mnew;
        lrun *= fac;
        oac[0] *= fac;
        oac[1] *= fac;
      }
      float p[32];
      #pragma unroll
      for (int t=0;t<32;t++) p[t] = exp2f(sv[t] - mrun);
      float a16[16];
      #pragma unroll
      for (int t=0;t<16;t++) a16[t] = p[t] + p[t+16];
      float a8[8];
      #pragma unroll
      for (int t=0;t<8;t++) a8[t] = a16[t] + a16[t+8];
      float rs = ((a8[0]+a8[1]) + (a8[2]+a8[3])) + ((a8[4]+a8[5]) + (a8[6]+a8[7]));
      rs += __shfl_xor(rs, 32);
      lrun += rs;

      // ---- pack P to bf16 pairs (kv-consecutive) ----
      u32 w[16];
      #pragma unroll
      for (int u=0;u<16;u++){
        asm("v_cvt_pk_bf16_f32 %0, %1, %2" : "=v"(w[u]) : "v"(p[2*u]), "v"(p[2*u+1]));
      }

      // ---- O^T += V^T · P^T ----
      __builtin_amdgcn_s_setprio(1);
      #pragma unroll
      for (int st=0; st<4; ++st){
        const int base = 8*(st>>1) + 4*(st&1);
        u32 x0 = h ? w[base+0] : w[base+2];
        u32 x1 = h ? w[base+1] : w[base+3];
        u32 r0 = (u32)__shfl_xor((int)x0, 32);
        u32 r1 = (u32)__shfl_xor((int)x1, 32);
        uint4 fw;
        fw.x = h ? r0 : w[base+0];
        fw.y = h ? r1 : w[base+1];
        fw.z = h ? w[base+2] : r0;
        fw.w = h ? w[base+3] : r1;
        bf16x8 pf = __builtin_bit_cast(bf16x8, fw);
        #pragma unroll
        for (int dt=0; dt<2; ++dt){
          bf16x8 vf = *(const bf16x8*)&Vb[(dt*32+ln31)*64 + swz[st]];
          oac[dt] = MFMA32(vf, pf, oac[dt]);
        }
      }
      __builtin_amdgcn_s_setprio(0);
    }

    __syncthreads();   // drains global_load_lds into cur^1; guards buffer reuse
    cur ^= 1;
  }

  // ---- normalize + store to (b, n, h*d) bf16 ----
  const float inv = 1.f / lrun;
  u16* orow = o + ((size_t)(b*SEQ) + myq)*HID + (size_t)(bh&15)*DH;
  #pragma unroll
  for (int dt=0; dt<2; ++dt)
    #pragma unroll
    for (int a=0; a<4; ++a){
      const int d0 = dt*32 + 8*a + 4*h;
      uint2 pk;
      pk.x = (u32)f2bf(oac[dt][4*a+0]*inv) | ((u32)f2bf(oac[dt][4*a+1]*inv)<<16);
      pk.y = (u32)f2bf(oac[dt][4*a+2]*inv) | ((u32)f2bf(oac[dt][4*a+3]*inv)<<16);
      *(uint2*)(orow + d0) = pk;
    }
}

// -----------------------------------------------------------------------------
extern "C" void kernel_launch(void* const* d_in, const int* in_sizes, int n_in,
                              void* d_out, int out_size, void* d_ws, size_t ws_size,
                              hipStream_t stream)
{
  const float* x_q = (const float*)d_in[0];
  const float* x_k = (const float*)d_in[1];
  const float* x_v = (const float*)d_in[2];
  const float* W_q = (const float*)d_in[3];
  const float* W_k = (const float*)d_in[4];
  const float* W_v = (const float*)d_in[5];
  const float* W_o = (const float*)d_in[6];
  const int*   pm  = (const int*)d_in[7];
  const int* caus = (const int*)d_in[8];
  const int* sp   = (const int*)d_in[9];

  char* ws = (char*)d_ws;
  float2* tab   = (float2*)ws;                      // 512 KiB
  u16*  v_ws    = (u16*)(ws + (1u<<20));            // 16 MiB (V^T: b,h,d,n)
  u16*  o_ws    = (u16*)(ws + (17u<<20));           // 16 MiB
  float* bias   = (float*)(ws + (33u<<20));         // 32 KiB
  u32*  flagb   = (u32*)(ws + (33u<<20) + (1u<<15));
  // q,k scratch live inside d_out (32 MiB); stream order makes this race-free.
  u16* q_ws = (u16*)d_out;
  u16* k_ws = ((u16*)d_out) + (size_t)MM*HID;

  rope_tab_kernel<<<SEQ*32/256, 256, 0, stream>>>(tab);
  mask_bias_kernel<<<1, 1024, 0, stream>>>(pm, bias, flagb, BB*SEQ);

  dim3 gg(MM/128, HID/128);
  gemm_k<0><<<gg, 256, 0, stream>>>(x_q, W_q, q_ws, tab);
  gemm_k<1><<<gg, 256, 0, stream>>>(x_k, W_k, k_ws, tab);
  gemm_k<2><<<gg, 256, 0, stream>>>(x_v, W_v, v_ws, tab);

  dim3 ga(SEQ/128, BB*HEADS);   // 16 paired blocks x 64 bh
  attn_k<<<ga, 256, 0, stream>>>(q_ws, k_ws, v_ws, o_ws, bias, flagb, caus, sp);

  gemm_k<3><<<gg, 256, 0, stream>>>(o_ws, W_o, d_out, tab);
}